// Round 1
// baseline (606.189 us; speedup 1.0000x reference)
//
#include <hip/hip_runtime.h>
#include <hip/hip_bf16.h>
#include <math.h>

// Problem: N=16384 anchors x D=4096 candidates, fp32.
// out = mean_i( logsumexp(logits_i/alpha) - logits_i[argmax(labels_i)]/alpha )
// Memory-bound: 512 MB reads (labels+logits), mask unused. Floor ~81 us @ 6.3 TB/s.

constexpr int Dk    = 4096;
constexpr int BLOCK = 256;   // 4 waves; each thread owns 16 elements (4 x float4)
constexpr int NBINS = 256;

__global__ __launch_bounds__(BLOCK) void nce_main(
    const float* __restrict__ labels, const float* __restrict__ logits,
    const float* __restrict__ alpha, float* __restrict__ bins)
{
    const int row = blockIdx.x;
    const int t   = threadIdx.x;
    const size_t base = (size_t)row * Dk;
    const float4* lab4 = reinterpret_cast<const float4*>(labels + base);
    const float4* lg4  = reinterpret_cast<const float4*>(logits + base);
    const float inv_alpha = 1.0f / alpha[0];

    // Pass 1: coalesced loads; keep logits in registers; track local logit max
    // and label (max, first-index, logit-at-index) triple.
    float4 gv[4];
    float m    = -INFINITY;
    float lmax = -INFINITY;
    int   lidx = 0x7fffffff;
    float lval = 0.0f;
#pragma unroll
    for (int k = 0; k < 4; ++k) {
        const int p = t + k * BLOCK;        // float4 index within row
        const float4 lv = lab4[p];
        const float4 g  = lg4[p];
        gv[k] = g;
        const float le[4] = {lv.x, lv.y, lv.z, lv.w};
        const float ge[4] = {g.x,  g.y,  g.z,  g.w};
#pragma unroll
        for (int e = 0; e < 4; ++e) {
            m = fmaxf(m, ge[e]);
            const int idx = 4 * p + e;
            // first-occurrence argmax semantics (tie -> smaller index)
            if (le[e] > lmax || (le[e] == lmax && idx < lidx)) {
                lmax = le[e]; lidx = idx; lval = ge[e];
            }
        }
    }

    // Block max of logits (for stable logsumexp): wave xor-reduce + LDS.
    __shared__ float s_m[BLOCK / 64];
#pragma unroll
    for (int off = 1; off < 64; off <<= 1)
        m = fmaxf(m, __shfl_xor(m, off));
    if ((t & 63) == 0) s_m[t >> 6] = m;
    __syncthreads();
    const float M = fmaxf(fmaxf(s_m[0], s_m[1]), fmaxf(s_m[2], s_m[3]));

    // Local sum of exp((x - M)/alpha) from registers (no global re-read).
    float s = 0.0f;
#pragma unroll
    for (int k = 0; k < 4; ++k) {
        s += __expf((gv[k].x - M) * inv_alpha);
        s += __expf((gv[k].y - M) * inv_alpha);
        s += __expf((gv[k].z - M) * inv_alpha);
        s += __expf((gv[k].w - M) * inv_alpha);
    }

    // Wave reduce: sum + argmax triple.
#pragma unroll
    for (int off = 32; off; off >>= 1) {
        s += __shfl_down(s, off);
        const float om = __shfl_down(lmax, off);
        const int   oi = __shfl_down(lidx, off);
        const float ov = __shfl_down(lval, off);
        if (om > lmax || (om == lmax && oi < lidx)) { lmax = om; lidx = oi; lval = ov; }
    }

    __shared__ float s_s[BLOCK / 64], s_lm[BLOCK / 64], s_lv[BLOCK / 64];
    __shared__ int   s_li[BLOCK / 64];
    if ((t & 63) == 0) {
        const int w = t >> 6;
        s_s[w] = s; s_lm[w] = lmax; s_li[w] = lidx; s_lv[w] = lval;
    }
    __syncthreads();

    if (t == 0) {
        const float S = s_s[0] + s_s[1] + s_s[2] + s_s[3];
        float bm = s_lm[0]; int bi = s_li[0]; float bv = s_lv[0];
#pragma unroll
        for (int w = 1; w < 4; ++w) {
            if (s_lm[w] > bm || (s_lm[w] == bm && s_li[w] < bi)) {
                bm = s_lm[w]; bi = s_li[w]; bv = s_lv[w];
            }
        }
        const float row_val = (M - bv) * inv_alpha + logf(S);
        // 256 bins -> only 64 same-address atomic collisions per bin.
        atomicAdd(bins + (blockIdx.x & (NBINS - 1)), row_val);
    }
}

__global__ __launch_bounds__(NBINS) void nce_finalize(
    const float* __restrict__ bins, float* __restrict__ out, float inv_n)
{
    const int t = threadIdx.x;
    float v = bins[t];
#pragma unroll
    for (int off = 32; off; off >>= 1) v += __shfl_down(v, off);
    __shared__ float s_w[NBINS / 64];
    if ((t & 63) == 0) s_w[t >> 6] = v;
    __syncthreads();
    if (t == 0) out[0] = (s_w[0] + s_w[1] + s_w[2] + s_w[3]) * inv_n;
}

extern "C" void kernel_launch(void* const* d_in, const int* in_sizes, int n_in,
                              void* d_out, int out_size, void* d_ws, size_t ws_size,
                              hipStream_t stream) {
    const float* labels = (const float*)d_in[0];
    const float* logits = (const float*)d_in[1];
    // d_in[2] = mask (unused by the reference math)
    const float* alpha  = (const float*)d_in[3];
    float* out  = (float*)d_out;
    float* bins = (float*)d_ws;

    const int N = in_sizes[0] / Dk;  // 16384

    // d_ws is poisoned to 0xAA before every launch — zero the bins (graph-safe).
    hipMemsetAsync(bins, 0, NBINS * sizeof(float), stream);
    nce_main<<<N, BLOCK, 0, stream>>>(labels, logits, alpha, bins);
    nce_finalize<<<1, NBINS, 0, stream>>>(bins, out, 1.0f / (float)N);
}

// Round 2
// 585.857 us; speedup vs baseline: 1.0347x; 1.0347x over previous
//
#include <hip/hip_runtime.h>
#include <math.h>

// NCE loss: N=16384 rows x D=4096, fp32.
// out = mean_i( logsumexp(logits_i/alpha) - logits_i[argmax(labels_i)]/alpha )
// Pure streaming read of labels+logits = 512 MB; mask never touched.
// HBM floor ~81 us @ 6.3 TB/s.

typedef float vf4 __attribute__((ext_vector_type(4)));

constexpr int Dk    = 4096;
constexpr int BLOCK = 256;   // 4 waves; each thread owns 16 elems per stream

__global__ __launch_bounds__(BLOCK) void nce_main(
    const float* __restrict__ labels, const float* __restrict__ logits,
    const float* __restrict__ alpha, float* __restrict__ bins)
{
    const int row = blockIdx.x;
    const int t   = threadIdx.x;
    const size_t base = (size_t)row * Dk;
    const vf4* lab4 = reinterpret_cast<const vf4*>(labels + base);
    const vf4* lg4  = reinterpret_cast<const vf4*>(logits + base);

    // Issue ALL 8 16-byte loads up front: 128 B/lane outstanding, nontemporal
    // (streaming, zero reuse) to avoid polluting L2.
    vf4 g[4], l[4];
#pragma unroll
    for (int k = 0; k < 4; ++k)
        g[k] = __builtin_nontemporal_load(lg4 + t + k * BLOCK);
#pragma unroll
    for (int k = 0; k < 4; ++k)
        l[k] = __builtin_nontemporal_load(lab4 + t + k * BLOCK);

    const float inv_alpha = 1.0f / alpha[0];

    // Register pass: logit max + label (max, first-idx, logit-at-idx) triple.
    float m    = -INFINITY;
    float lmax = -INFINITY;
    int   lidx = 0x7fffffff;
    float lval = 0.0f;
#pragma unroll
    for (int k = 0; k < 4; ++k) {
#pragma unroll
        for (int e = 0; e < 4; ++e) {
            const float ge = g[k][e];
            const float le = l[k][e];
            m = fmaxf(m, ge);
            const int idx = 4 * (t + k * BLOCK) + e;
            // first-occurrence argmax (tie -> smaller index), matches jnp.argmax
            if (le > lmax || (le == lmax && idx < lidx)) {
                lmax = le; lidx = idx; lval = ge;
            }
        }
    }

    // Block max of logits: wave xor-reduce + 4-entry LDS.
    __shared__ float s_m[BLOCK / 64];
#pragma unroll
    for (int off = 1; off < 64; off <<= 1)
        m = fmaxf(m, __shfl_xor(m, off));
    if ((t & 63) == 0) s_m[t >> 6] = m;
    __syncthreads();
    const float M = fmaxf(fmaxf(s_m[0], s_m[1]), fmaxf(s_m[2], s_m[3]));

    // Local sum of exp((x - M)/alpha) straight from registers.
    float s = 0.0f;
#pragma unroll
    for (int k = 0; k < 4; ++k) {
        s += __expf((g[k][0] - M) * inv_alpha);
        s += __expf((g[k][1] - M) * inv_alpha);
        s += __expf((g[k][2] - M) * inv_alpha);
        s += __expf((g[k][3] - M) * inv_alpha);
    }

    // Wave reduce: sum + argmax triple.
#pragma unroll
    for (int off = 32; off; off >>= 1) {
        s += __shfl_down(s, off);
        const float om = __shfl_down(lmax, off);
        const int   oi = __shfl_down(lidx, off);
        const float ov = __shfl_down(lval, off);
        if (om > lmax || (om == lmax && oi < lidx)) { lmax = om; lidx = oi; lval = ov; }
    }

    __shared__ float s_s[BLOCK / 64], s_lm[BLOCK / 64], s_lv[BLOCK / 64];
    __shared__ int   s_li[BLOCK / 64];
    if ((t & 63) == 0) {
        const int w = t >> 6;
        s_s[w] = s; s_lm[w] = lmax; s_li[w] = lidx; s_lv[w] = lval;
    }
    __syncthreads();

    if (t == 0) {
        const float S = s_s[0] + s_s[1] + s_s[2] + s_s[3];
        float bm = s_lm[0]; int bi = s_li[0]; float bv = s_lv[0];
#pragma unroll
        for (int w = 1; w < 4; ++w) {
            if (s_lm[w] > bm || (s_lm[w] == bm && s_li[w] < bi)) {
                bm = s_lm[w]; bi = s_li[w]; bv = s_lv[w];
            }
        }
        // Plain store — every row slot is written, no init/atomics needed.
        bins[row] = (M - bv) * inv_alpha + logf(S);
    }
}

// Reduce 16384 per-row values -> mean. One block, 256 threads x 64 values.
__global__ __launch_bounds__(BLOCK) void nce_finalize(
    const float* __restrict__ bins, float* __restrict__ out, int n, float inv_n)
{
    const int t = threadIdx.x;
    float v = 0.0f;
    for (int i = t; i < n; i += BLOCK) v += bins[i];
#pragma unroll
    for (int off = 32; off; off >>= 1) v += __shfl_down(v, off);
    __shared__ float s_w[BLOCK / 64];
    if ((t & 63) == 0) s_w[t >> 6] = v;
    __syncthreads();
    if (t == 0) out[0] = (s_w[0] + s_w[1] + s_w[2] + s_w[3]) * inv_n;
}

extern "C" void kernel_launch(void* const* d_in, const int* in_sizes, int n_in,
                              void* d_out, int out_size, void* d_ws, size_t ws_size,
                              hipStream_t stream) {
    const float* labels = (const float*)d_in[0];
    const float* logits = (const float*)d_in[1];
    // d_in[2] = mask (unused by the reference math)
    const float* alpha  = (const float*)d_in[3];
    float* out  = (float*)d_out;
    float* bins = (float*)d_ws;   // N floats = 64 KB scratch

    const int N = in_sizes[0] / Dk;  // 16384

    nce_main<<<N, BLOCK, 0, stream>>>(labels, logits, alpha, bins);
    nce_finalize<<<1, BLOCK, 0, stream>>>(bins, out, N, 1.0f / (float)N);
}